// Round 3
// baseline (108.673 us; speedup 1.0000x reference)
//
#include <hip/hip_runtime.h>

// Inclusive prefix-compose of rigid transforms along N=32 per batch row.
// x: float[B][32][3][4];  out[b][n] = x[b][0] * ... * x[b][n]  (4x4 homog product)
//
// 4 transforms per thread, 8 threads per row. Direct strided global float4
// loads/stores (192 B per thread, dense 12 KB per wave window — no LDS).
// Width-8 segmented shuffle scan of chunk products.

#define BLOCK 256
#define F4C   12   // float4 per chunk (4 transforms * 3 float4)

struct Xf {
    float a00,a01,a02,a03;   // r00 r01 r02 tx
    float a10,a11,a12,a13;   // r10 r11 r12 ty
    float a20,a21,a22,a23;   // r20 r21 r22 tz
};

__device__ __forceinline__ Xf compose(const Xf& A, const Xf& B) {
    Xf D;
    D.a00 = fmaf(A.a00,B.a00, fmaf(A.a01,B.a10, A.a02*B.a20));
    D.a01 = fmaf(A.a00,B.a01, fmaf(A.a01,B.a11, A.a02*B.a21));
    D.a02 = fmaf(A.a00,B.a02, fmaf(A.a01,B.a12, A.a02*B.a22));
    D.a03 = fmaf(A.a00,B.a03, fmaf(A.a01,B.a13, fmaf(A.a02,B.a23, A.a03)));
    D.a10 = fmaf(A.a10,B.a00, fmaf(A.a11,B.a10, A.a12*B.a20));
    D.a11 = fmaf(A.a10,B.a01, fmaf(A.a11,B.a11, A.a12*B.a21));
    D.a12 = fmaf(A.a10,B.a02, fmaf(A.a11,B.a12, A.a12*B.a22));
    D.a13 = fmaf(A.a10,B.a03, fmaf(A.a11,B.a13, fmaf(A.a12,B.a23, A.a13)));
    D.a20 = fmaf(A.a20,B.a00, fmaf(A.a21,B.a10, A.a22*B.a20));
    D.a21 = fmaf(A.a20,B.a01, fmaf(A.a21,B.a11, A.a22*B.a21));
    D.a22 = fmaf(A.a20,B.a02, fmaf(A.a21,B.a12, A.a22*B.a22));
    D.a23 = fmaf(A.a20,B.a03, fmaf(A.a21,B.a13, fmaf(A.a22,B.a23, A.a23)));
    return D;
}

__device__ __forceinline__ Xf shfl_up_xf(const Xf& V, int d) {
    Xf U;
    U.a00 = __shfl_up(V.a00, d, 8);  U.a01 = __shfl_up(V.a01, d, 8);
    U.a02 = __shfl_up(V.a02, d, 8);  U.a03 = __shfl_up(V.a03, d, 8);
    U.a10 = __shfl_up(V.a10, d, 8);  U.a11 = __shfl_up(V.a11, d, 8);
    U.a12 = __shfl_up(V.a12, d, 8);  U.a13 = __shfl_up(V.a13, d, 8);
    U.a20 = __shfl_up(V.a20, d, 8);  U.a21 = __shfl_up(V.a21, d, 8);
    U.a22 = __shfl_up(V.a22, d, 8);  U.a23 = __shfl_up(V.a23, d, 8);
    return U;
}

__device__ __forceinline__ Xf unpack(const float4& v0, const float4& v1, const float4& v2) {
    Xf T;
    T.a00=v0.x; T.a01=v0.y; T.a02=v0.z; T.a03=v0.w;
    T.a10=v1.x; T.a11=v1.y; T.a12=v1.z; T.a13=v1.w;
    T.a20=v2.x; T.a21=v2.y; T.a22=v2.z; T.a23=v2.w;
    return T;
}

__device__ __forceinline__ void pack(const Xf& T, float4& v0, float4& v1, float4& v2) {
    v0 = make_float4(T.a00,T.a01,T.a02,T.a03);
    v1 = make_float4(T.a10,T.a11,T.a12,T.a13);
    v2 = make_float4(T.a20,T.a21,T.a22,T.a23);
}

__global__ __launch_bounds__(BLOCK) void compose_scan4_direct(
    const float4* __restrict__ x, float4* __restrict__ out, long long nchunks)
{
    const long long g = (long long)blockIdx.x * BLOCK + threadIdx.x;
    if (g >= nchunks) return;
    const long long cb = g * F4C;     // chunk base in float4 units

    // ---- 1. load own chunk: 12 consecutive float4 (192 B) ----
    float4 v[F4C];
    #pragma unroll
    for (int j = 0; j < F4C; ++j) v[j] = x[cb + j];

    Xf c0 = unpack(v[0], v[1], v[2]);
    Xf c1 = unpack(v[3], v[4], v[5]);
    Xf c2 = unpack(v[6], v[7], v[8]);
    Xf c3 = unpack(v[9], v[10], v[11]);

    // ---- 2. serial inclusive compose within the chunk ----
    c1 = compose(c0, c1);
    c2 = compose(c1, c2);
    c3 = compose(c2, c3);

    // ---- 3. width-8 segmented scan of chunk totals ----
    const int sl = threadIdx.x & 7;
    Xf p = c3;
    #pragma unroll
    for (int d = 1; d < 8; d <<= 1) {
        Xf u = shfl_up_xf(p, d);
        Xf np = compose(u, p);
        if (sl >= d) p = np;
    }

    // exclusive prefix of this chunk
    Xf e = shfl_up_xf(p, 1);
    if (sl == 0) {
        e.a00=1.f; e.a01=0.f; e.a02=0.f; e.a03=0.f;
        e.a10=0.f; e.a11=1.f; e.a12=0.f; e.a13=0.f;
        e.a20=0.f; e.a21=0.f; e.a22=1.f; e.a23=0.f;
    }

    // ---- 4. apply exclusive prefix (o3 == p already) ----
    Xf o0 = compose(e, c0);
    Xf o1 = compose(e, c1);
    Xf o2 = compose(e, c2);

    pack(o0, v[0], v[1], v[2]);
    pack(o1, v[3], v[4], v[5]);
    pack(o2, v[6], v[7], v[8]);
    pack(p,  v[9], v[10], v[11]);

    // ---- 5. store: 12 consecutive float4 ----
    #pragma unroll
    for (int j = 0; j < F4C; ++j) out[cb + j] = v[j];
}

extern "C" void kernel_launch(void* const* d_in, const int* in_sizes, int n_in,
                              void* d_out, int out_size, void* d_ws, size_t ws_size,
                              hipStream_t stream) {
    const float4* x = (const float4*)d_in[0];
    float4* out = (float4*)d_out;

    const long long nrows = in_sizes[0] / 384;   // B (32 transforms * 12 floats)
    const long long nchunks = nrows * 8;         // 4 transforms per chunk
    const int grid = (int)((nchunks + BLOCK - 1) / BLOCK);

    compose_scan4_direct<<<grid, BLOCK, 0, stream>>>(x, out, nchunks);
}

// Round 4
// 77.765 us; speedup vs baseline: 1.3974x; 1.3974x over previous
//
#include <hip/hip_runtime.h>

// Inclusive prefix-compose of rigid transforms along N=32 per batch row.
// x: float[B][32][3][4];  out[b][n] = x[b][0] * ... * x[b][n]  (4x4 homog product)
//
// 2 transforms per thread, 16 threads per row, 4 rows per wave.
// Global <-> LDS wave-private staging (6KB + pad per wave, NO barriers):
//   - global access fully contiguous (lane l moves float4 wbase + l + 64j)
//   - pad 1 float4 per 6 -> chunk reads at slot 7l+j, conflict-free banks
// Width-16 segmented shuffle scan of chunk products.

#define BLOCK 128
#define WPB   (BLOCK / 64)   // waves per block
#define F4W   384            // float4 per wave strip (4 rows * 32 xf * 3 f4)
#define F4WP  448            // padded slots per wave (k + k/6, k<384 -> <448)

struct Xf {
    float a00,a01,a02,a03;   // r00 r01 r02 tx
    float a10,a11,a12,a13;   // r10 r11 r12 ty
    float a20,a21,a22,a23;   // r20 r21 r22 tz
};

__device__ __forceinline__ Xf compose(const Xf& A, const Xf& B) {
    Xf D;
    D.a00 = fmaf(A.a00,B.a00, fmaf(A.a01,B.a10, A.a02*B.a20));
    D.a01 = fmaf(A.a00,B.a01, fmaf(A.a01,B.a11, A.a02*B.a21));
    D.a02 = fmaf(A.a00,B.a02, fmaf(A.a01,B.a12, A.a02*B.a22));
    D.a03 = fmaf(A.a00,B.a03, fmaf(A.a01,B.a13, fmaf(A.a02,B.a23, A.a03)));
    D.a10 = fmaf(A.a10,B.a00, fmaf(A.a11,B.a10, A.a12*B.a20));
    D.a11 = fmaf(A.a10,B.a01, fmaf(A.a11,B.a11, A.a12*B.a21));
    D.a12 = fmaf(A.a10,B.a02, fmaf(A.a11,B.a12, A.a12*B.a22));
    D.a13 = fmaf(A.a10,B.a03, fmaf(A.a11,B.a13, fmaf(A.a12,B.a23, A.a13)));
    D.a20 = fmaf(A.a20,B.a00, fmaf(A.a21,B.a10, A.a22*B.a20));
    D.a21 = fmaf(A.a20,B.a01, fmaf(A.a21,B.a11, A.a22*B.a21));
    D.a22 = fmaf(A.a20,B.a02, fmaf(A.a21,B.a12, A.a22*B.a22));
    D.a23 = fmaf(A.a20,B.a03, fmaf(A.a21,B.a13, fmaf(A.a22,B.a23, A.a23)));
    return D;
}

__device__ __forceinline__ Xf shfl_up_xf(const Xf& V, int d) {
    Xf U;
    U.a00 = __shfl_up(V.a00, d, 16);  U.a01 = __shfl_up(V.a01, d, 16);
    U.a02 = __shfl_up(V.a02, d, 16);  U.a03 = __shfl_up(V.a03, d, 16);
    U.a10 = __shfl_up(V.a10, d, 16);  U.a11 = __shfl_up(V.a11, d, 16);
    U.a12 = __shfl_up(V.a12, d, 16);  U.a13 = __shfl_up(V.a13, d, 16);
    U.a20 = __shfl_up(V.a20, d, 16);  U.a21 = __shfl_up(V.a21, d, 16);
    U.a22 = __shfl_up(V.a22, d, 16);  U.a23 = __shfl_up(V.a23, d, 16);
    return U;
}

__device__ __forceinline__ Xf unpack(const float4& v0, const float4& v1, const float4& v2) {
    Xf T;
    T.a00=v0.x; T.a01=v0.y; T.a02=v0.z; T.a03=v0.w;
    T.a10=v1.x; T.a11=v1.y; T.a12=v1.z; T.a13=v1.w;
    T.a20=v2.x; T.a21=v2.y; T.a22=v2.z; T.a23=v2.w;
    return T;
}

__global__ __launch_bounds__(BLOCK) void compose_scan2_wstage(
    const float4* __restrict__ x, float4* __restrict__ out, int nwaves)
{
    __shared__ float4 lds[WPB * F4WP];   // 14 KB
    const int wib = threadIdx.x >> 6;    // wave within block
    const int l   = threadIdx.x & 63;    // lane
    const int wave = blockIdx.x * WPB + wib;
    if (wave >= nwaves) return;          // wave-uniform, no barriers used

    const int wbase = wave * F4W;        // global f4 base (fits in int: <12.6M)
    float4* L = lds + wib * F4WP;        // wave-private LDS region

    // ---- 1. contiguous global -> padded LDS ----
    #pragma unroll
    for (int j = 0; j < 6; ++j) {
        const int k = l + 64 * j;
        L[k + k / 6] = x[wbase + k];
    }
    asm volatile("s_waitcnt lgkmcnt(0)" ::: "memory");

    // ---- 2. read own chunk (2 transforms): slots 7l .. 7l+5, bank-clean ----
    float4 v[6];
    #pragma unroll
    for (int j = 0; j < 6; ++j) v[j] = L[7 * l + j];

    Xf c0 = unpack(v[0], v[1], v[2]);
    Xf c1 = unpack(v[3], v[4], v[5]);

    // ---- 3. serial compose within chunk ----
    c1 = compose(c0, c1);

    // ---- 4. width-16 segmented scan of chunk totals ----
    const int sl = l & 15;
    Xf p = c1;
    #pragma unroll
    for (int d = 1; d < 16; d <<= 1) {
        Xf u = shfl_up_xf(p, d);
        Xf np = compose(u, p);
        if (sl >= d) p = np;
    }

    // exclusive prefix of this chunk
    Xf e = shfl_up_xf(p, 1);
    if (sl == 0) {
        e.a00=1.f; e.a01=0.f; e.a02=0.f; e.a03=0.f;
        e.a10=0.f; e.a11=1.f; e.a12=0.f; e.a13=0.f;
        e.a20=0.f; e.a21=0.f; e.a22=1.f; e.a23=0.f;
    }

    // ---- 5. outputs: o0 = e*c0, o1 = p (inclusive) ----
    Xf o0 = compose(e, c0);

    v[0] = make_float4(o0.a00,o0.a01,o0.a02,o0.a03);
    v[1] = make_float4(o0.a10,o0.a11,o0.a12,o0.a13);
    v[2] = make_float4(o0.a20,o0.a21,o0.a22,o0.a23);
    v[3] = make_float4(p.a00, p.a01, p.a02, p.a03);
    v[4] = make_float4(p.a10, p.a11, p.a12, p.a13);
    v[5] = make_float4(p.a20, p.a21, p.a22, p.a23);

    // ---- 6. own chunk -> padded LDS (all reads above already done, lockstep) ----
    #pragma unroll
    for (int j = 0; j < 6; ++j) L[7 * l + j] = v[j];
    asm volatile("s_waitcnt lgkmcnt(0)" ::: "memory");

    // ---- 7. padded LDS -> contiguous global ----
    #pragma unroll
    for (int j = 0; j < 6; ++j) {
        const int k = l + 64 * j;
        out[wbase + k] = L[k + k / 6];
    }
}

extern "C" void kernel_launch(void* const* d_in, const int* in_sizes, int n_in,
                              void* d_out, int out_size, void* d_ws, size_t ws_size,
                              hipStream_t stream) {
    const float4* x = (const float4*)d_in[0];
    float4* out = (float4*)d_out;

    const int nrows  = in_sizes[0] / 384;     // B (32 xf * 12 floats per row)
    const int nwaves = nrows / 4;             // 4 rows per wave (B=131072 -> exact)
    const int grid   = (nwaves + WPB - 1) / WPB;

    compose_scan2_wstage<<<grid, BLOCK, 0, stream>>>(x, out, nwaves);
}

// Round 5
// 63.896 us; speedup vs baseline: 1.7008x; 1.2171x over previous
//
#include <hip/hip_runtime.h>

// Inclusive prefix-compose of rigid transforms along N=32 per batch row.
// x: float[B][32][3][4];  out[b][n] = x[b][0] * ... * x[b][n]  (4x4 homog product)
//
// 2 transforms per thread, 16 threads per row, 4 rows per wave.
// Global <-> LDS wave-private staging (6KB + pad per wave, NO barriers):
//   - global access fully contiguous (lane l moves float4 wbase + l + 64j)
//   - pad 1 float4 per 6 -> chunk reads at slot 7l+j, conflict-free banks
// Width-16 segmented shuffle scan of chunk products.
// Output stores are NON-TEMPORAL (streaming): output is never re-read, so
// keeping it out of L2/L3 lets the 201 MB input stay resident in the 256 MB
// Infinity Cache across graph replays (reads become L3 hits).

#define BLOCK 128
#define WPB   (BLOCK / 64)   // waves per block
#define F4W   384            // float4 per wave strip (4 rows * 32 xf * 3 f4)
#define F4WP  448            // padded slots per wave (k + k/6, k<384 -> <448)

typedef __attribute__((ext_vector_type(4))) float f4v;

struct Xf {
    float a00,a01,a02,a03;   // r00 r01 r02 tx
    float a10,a11,a12,a13;   // r10 r11 r12 ty
    float a20,a21,a22,a23;   // r20 r21 r22 tz
};

__device__ __forceinline__ Xf compose(const Xf& A, const Xf& B) {
    Xf D;
    D.a00 = fmaf(A.a00,B.a00, fmaf(A.a01,B.a10, A.a02*B.a20));
    D.a01 = fmaf(A.a00,B.a01, fmaf(A.a01,B.a11, A.a02*B.a21));
    D.a02 = fmaf(A.a00,B.a02, fmaf(A.a01,B.a12, A.a02*B.a22));
    D.a03 = fmaf(A.a00,B.a03, fmaf(A.a01,B.a13, fmaf(A.a02,B.a23, A.a03)));
    D.a10 = fmaf(A.a10,B.a00, fmaf(A.a11,B.a10, A.a12*B.a20));
    D.a11 = fmaf(A.a10,B.a01, fmaf(A.a11,B.a11, A.a12*B.a21));
    D.a12 = fmaf(A.a10,B.a02, fmaf(A.a11,B.a12, A.a12*B.a22));
    D.a13 = fmaf(A.a10,B.a03, fmaf(A.a11,B.a13, fmaf(A.a12,B.a23, A.a13)));
    D.a20 = fmaf(A.a20,B.a00, fmaf(A.a21,B.a10, A.a22*B.a20));
    D.a21 = fmaf(A.a20,B.a01, fmaf(A.a21,B.a11, A.a22*B.a21));
    D.a22 = fmaf(A.a20,B.a02, fmaf(A.a21,B.a12, A.a22*B.a22));
    D.a23 = fmaf(A.a20,B.a03, fmaf(A.a21,B.a13, fmaf(A.a22,B.a23, A.a23)));
    return D;
}

__device__ __forceinline__ Xf shfl_up_xf(const Xf& V, int d) {
    Xf U;
    U.a00 = __shfl_up(V.a00, d, 16);  U.a01 = __shfl_up(V.a01, d, 16);
    U.a02 = __shfl_up(V.a02, d, 16);  U.a03 = __shfl_up(V.a03, d, 16);
    U.a10 = __shfl_up(V.a10, d, 16);  U.a11 = __shfl_up(V.a11, d, 16);
    U.a12 = __shfl_up(V.a12, d, 16);  U.a13 = __shfl_up(V.a13, d, 16);
    U.a20 = __shfl_up(V.a20, d, 16);  U.a21 = __shfl_up(V.a21, d, 16);
    U.a22 = __shfl_up(V.a22, d, 16);  U.a23 = __shfl_up(V.a23, d, 16);
    return U;
}

__device__ __forceinline__ Xf unpack(const f4v& v0, const f4v& v1, const f4v& v2) {
    Xf T;
    T.a00=v0.x; T.a01=v0.y; T.a02=v0.z; T.a03=v0.w;
    T.a10=v1.x; T.a11=v1.y; T.a12=v1.z; T.a13=v1.w;
    T.a20=v2.x; T.a21=v2.y; T.a22=v2.z; T.a23=v2.w;
    return T;
}

__global__ __launch_bounds__(BLOCK) void compose_scan2_wstage_nt(
    const f4v* __restrict__ x, f4v* __restrict__ out, int nwaves)
{
    __shared__ f4v lds[WPB * F4WP];      // 14 KB
    const int wib = threadIdx.x >> 6;    // wave within block
    const int l   = threadIdx.x & 63;    // lane
    const int wave = blockIdx.x * WPB + wib;
    if (wave >= nwaves) return;          // wave-uniform, no barriers used

    const int wbase = wave * F4W;        // global f4 base (fits in int: <12.6M)
    f4v* L = lds + wib * F4WP;           // wave-private LDS region

    // ---- 1. contiguous global -> padded LDS ----
    #pragma unroll
    for (int j = 0; j < 6; ++j) {
        const int k = l + 64 * j;
        L[k + k / 6] = x[wbase + k];
    }
    asm volatile("s_waitcnt lgkmcnt(0)" ::: "memory");

    // ---- 2. read own chunk (2 transforms): slots 7l .. 7l+5, bank-clean ----
    f4v v[6];
    #pragma unroll
    for (int j = 0; j < 6; ++j) v[j] = L[7 * l + j];

    Xf c0 = unpack(v[0], v[1], v[2]);
    Xf c1 = unpack(v[3], v[4], v[5]);

    // ---- 3. serial compose within chunk ----
    c1 = compose(c0, c1);

    // ---- 4. width-16 segmented scan of chunk totals ----
    const int sl = l & 15;
    Xf p = c1;
    #pragma unroll
    for (int d = 1; d < 16; d <<= 1) {
        Xf u = shfl_up_xf(p, d);
        Xf np = compose(u, p);
        if (sl >= d) p = np;
    }

    // exclusive prefix of this chunk
    Xf e = shfl_up_xf(p, 1);
    if (sl == 0) {
        e.a00=1.f; e.a01=0.f; e.a02=0.f; e.a03=0.f;
        e.a10=0.f; e.a11=1.f; e.a12=0.f; e.a13=0.f;
        e.a20=0.f; e.a21=0.f; e.a22=1.f; e.a23=0.f;
    }

    // ---- 5. outputs: o0 = e*c0, o1 = p (inclusive) ----
    Xf o0 = compose(e, c0);

    v[0] = (f4v){o0.a00,o0.a01,o0.a02,o0.a03};
    v[1] = (f4v){o0.a10,o0.a11,o0.a12,o0.a13};
    v[2] = (f4v){o0.a20,o0.a21,o0.a22,o0.a23};
    v[3] = (f4v){p.a00, p.a01, p.a02, p.a03};
    v[4] = (f4v){p.a10, p.a11, p.a12, p.a13};
    v[5] = (f4v){p.a20, p.a21, p.a22, p.a23};

    // ---- 6. own chunk -> padded LDS (all reads above already done, lockstep) ----
    #pragma unroll
    for (int j = 0; j < 6; ++j) L[7 * l + j] = v[j];
    asm volatile("s_waitcnt lgkmcnt(0)" ::: "memory");

    // ---- 7. padded LDS -> contiguous global, streaming (evict-first) ----
    #pragma unroll
    for (int j = 0; j < 6; ++j) {
        const int k = l + 64 * j;
        __builtin_nontemporal_store(L[k + k / 6], out + wbase + k);
    }
}

extern "C" void kernel_launch(void* const* d_in, const int* in_sizes, int n_in,
                              void* d_out, int out_size, void* d_ws, size_t ws_size,
                              hipStream_t stream) {
    const f4v* x = (const f4v*)d_in[0];
    f4v* out = (f4v*)d_out;

    const int nrows  = in_sizes[0] / 384;     // B (32 xf * 12 floats per row)
    const int nwaves = nrows / 4;             // 4 rows per wave (B=131072 -> exact)
    const int grid   = (nwaves + WPB - 1) / WPB;

    compose_scan2_wstage_nt<<<grid, BLOCK, 0, stream>>>(x, out, nwaves);
}

// Round 6
// 63.479 us; speedup vs baseline: 1.7119x; 1.0066x over previous
//
#include <hip/hip_runtime.h>

// Inclusive prefix-compose of rigid transforms along N=32 per batch row.
// x: float[B][32][3][4];  out[b][n] = x[b][0] * ... * x[b][n]  (4x4 homog product)
//
// 2 transforms per thread, 16 threads per row, 4 rows per wave.
// Global <-> LDS wave-private staging (6KB + pad per wave, NO barriers).
// Width-16 segmented scan done with DPP row_shr (VALU) instead of
// ds_bpermute (__shfl) -- keeps the scan OFF the LDS pipe, which profiling
// showed was the busiest pipe (staging + 60 bpermutes/wave ~ 35 us/CU).
// Output stores are NON-TEMPORAL so the 201 MB input stays L3-resident.

#define BLOCK 128
#define WPB   (BLOCK / 64)   // waves per block
#define F4W   384            // float4 per wave strip (4 rows * 32 xf * 3 f4)
#define F4WP  448            // padded slots per wave (k + k/6, k<384 -> <448)

typedef __attribute__((ext_vector_type(4))) float f4v;

struct Xf {
    float a00,a01,a02,a03;   // r00 r01 r02 tx
    float a10,a11,a12,a13;   // r10 r11 r12 ty
    float a20,a21,a22,a23;   // r20 r21 r22 tz
};

__device__ __forceinline__ Xf compose(const Xf& A, const Xf& B) {
    Xf D;
    D.a00 = fmaf(A.a00,B.a00, fmaf(A.a01,B.a10, A.a02*B.a20));
    D.a01 = fmaf(A.a00,B.a01, fmaf(A.a01,B.a11, A.a02*B.a21));
    D.a02 = fmaf(A.a00,B.a02, fmaf(A.a01,B.a12, A.a02*B.a22));
    D.a03 = fmaf(A.a00,B.a03, fmaf(A.a01,B.a13, fmaf(A.a02,B.a23, A.a03)));
    D.a10 = fmaf(A.a10,B.a00, fmaf(A.a11,B.a10, A.a12*B.a20));
    D.a11 = fmaf(A.a10,B.a01, fmaf(A.a11,B.a11, A.a12*B.a21));
    D.a12 = fmaf(A.a10,B.a02, fmaf(A.a11,B.a12, A.a12*B.a22));
    D.a13 = fmaf(A.a10,B.a03, fmaf(A.a11,B.a13, fmaf(A.a12,B.a23, A.a13)));
    D.a20 = fmaf(A.a20,B.a00, fmaf(A.a21,B.a10, A.a22*B.a20));
    D.a21 = fmaf(A.a20,B.a01, fmaf(A.a21,B.a11, A.a22*B.a21));
    D.a22 = fmaf(A.a20,B.a02, fmaf(A.a21,B.a12, A.a22*B.a22));
    D.a23 = fmaf(A.a20,B.a03, fmaf(A.a21,B.a13, fmaf(A.a22,B.a23, A.a23)));
    return D;
}

// lane i <- lane i-D within each 16-lane row (DPP row_shr:D, VALU pipe).
// Lanes with sl<D get stale data -- caller masks with (sl>=D) predicate.
template<int D>
__device__ __forceinline__ float shup(float v) {
    int r = __builtin_amdgcn_update_dpp(0, __float_as_int(v),
                                        0x110 | D, 0xf, 0xf, false);
    return __int_as_float(r);
}

template<int D>
__device__ __forceinline__ Xf shfl_up_xf(const Xf& V) {
    Xf U;
    U.a00 = shup<D>(V.a00);  U.a01 = shup<D>(V.a01);
    U.a02 = shup<D>(V.a02);  U.a03 = shup<D>(V.a03);
    U.a10 = shup<D>(V.a10);  U.a11 = shup<D>(V.a11);
    U.a12 = shup<D>(V.a12);  U.a13 = shup<D>(V.a13);
    U.a20 = shup<D>(V.a20);  U.a21 = shup<D>(V.a21);
    U.a22 = shup<D>(V.a22);  U.a23 = shup<D>(V.a23);
    return U;
}

__device__ __forceinline__ Xf unpack(const f4v& v0, const f4v& v1, const f4v& v2) {
    Xf T;
    T.a00=v0.x; T.a01=v0.y; T.a02=v0.z; T.a03=v0.w;
    T.a10=v1.x; T.a11=v1.y; T.a12=v1.z; T.a13=v1.w;
    T.a20=v2.x; T.a21=v2.y; T.a22=v2.z; T.a23=v2.w;
    return T;
}

__global__ __launch_bounds__(BLOCK) void compose_scan2_dpp(
    const f4v* __restrict__ x, f4v* __restrict__ out, int nwaves)
{
    __shared__ f4v lds[WPB * F4WP];      // 14 KB
    const int wib = threadIdx.x >> 6;    // wave within block
    const int l   = threadIdx.x & 63;    // lane
    const int wave = blockIdx.x * WPB + wib;
    if (wave >= nwaves) return;          // wave-uniform, no barriers used

    const int wbase = wave * F4W;        // global f4 base (fits in int: <12.6M)
    f4v* L = lds + wib * F4WP;           // wave-private LDS region

    // ---- 1. contiguous global -> padded LDS ----
    #pragma unroll
    for (int j = 0; j < 6; ++j) {
        const int k = l + 64 * j;
        L[k + k / 6] = x[wbase + k];
    }
    asm volatile("s_waitcnt lgkmcnt(0)" ::: "memory");

    // ---- 2. read own chunk (2 transforms): slots 7l .. 7l+5, bank-clean ----
    f4v v[6];
    #pragma unroll
    for (int j = 0; j < 6; ++j) v[j] = L[7 * l + j];

    Xf c0 = unpack(v[0], v[1], v[2]);
    Xf c1 = unpack(v[3], v[4], v[5]);

    // ---- 3. serial compose within chunk ----
    c1 = compose(c0, c1);

    // ---- 4. width-16 segmented scan of chunk totals (DPP, VALU pipe) ----
    const int sl = l & 15;
    Xf p = c1;
    { Xf u = shfl_up_xf<1>(p); Xf np = compose(u, p); if (sl >= 1) p = np; }
    { Xf u = shfl_up_xf<2>(p); Xf np = compose(u, p); if (sl >= 2) p = np; }
    { Xf u = shfl_up_xf<4>(p); Xf np = compose(u, p); if (sl >= 4) p = np; }
    { Xf u = shfl_up_xf<8>(p); Xf np = compose(u, p); if (sl >= 8) p = np; }

    // exclusive prefix of this chunk
    Xf e = shfl_up_xf<1>(p);
    if (sl == 0) {
        e.a00=1.f; e.a01=0.f; e.a02=0.f; e.a03=0.f;
        e.a10=0.f; e.a11=1.f; e.a12=0.f; e.a13=0.f;
        e.a20=0.f; e.a21=0.f; e.a22=1.f; e.a23=0.f;
    }

    // ---- 5. outputs: o0 = e*c0, o1 = p (inclusive) ----
    Xf o0 = compose(e, c0);

    v[0] = (f4v){o0.a00,o0.a01,o0.a02,o0.a03};
    v[1] = (f4v){o0.a10,o0.a11,o0.a12,o0.a13};
    v[2] = (f4v){o0.a20,o0.a21,o0.a22,o0.a23};
    v[3] = (f4v){p.a00, p.a01, p.a02, p.a03};
    v[4] = (f4v){p.a10, p.a11, p.a12, p.a13};
    v[5] = (f4v){p.a20, p.a21, p.a22, p.a23};

    // ---- 6. own chunk -> padded LDS (all reads above already done, lockstep) ----
    #pragma unroll
    for (int j = 0; j < 6; ++j) L[7 * l + j] = v[j];
    asm volatile("s_waitcnt lgkmcnt(0)" ::: "memory");

    // ---- 7. padded LDS -> contiguous global, streaming (evict-first) ----
    #pragma unroll
    for (int j = 0; j < 6; ++j) {
        const int k = l + 64 * j;
        __builtin_nontemporal_store(L[k + k / 6], out + wbase + k);
    }
}

extern "C" void kernel_launch(void* const* d_in, const int* in_sizes, int n_in,
                              void* d_out, int out_size, void* d_ws, size_t ws_size,
                              hipStream_t stream) {
    const f4v* x = (const f4v*)d_in[0];
    f4v* out = (f4v*)d_out;

    const int nrows  = in_sizes[0] / 384;     // B (32 xf * 12 floats per row)
    const int nwaves = nrows / 4;             // 4 rows per wave (B=131072 -> exact)
    const int grid   = (nwaves + WPB - 1) / WPB;

    compose_scan2_dpp<<<grid, BLOCK, 0, stream>>>(x, out, nwaves);
}